// Round 8
// baseline (66.105 us; speedup 1.0000x reference)
//
#include <hip/hip_runtime.h>
#include <math.h>

#define N 512
#define BATCH 256
#define KTOP 16
#define NLAYERS 45
#define NPAIRS 256

// Cross-lane xor via DPP (VALU pipe, NOT the DS pipe):
//   xor1 = quad_perm[1,0,3,2] = 0xB1; xor2 = quad_perm[2,3,0,1] = 0x4E;
//   xor8 = row_ror:8 = 0x128 (rotate by half a 16-lane row == xor 8).
//   xor4 = select(row_shl:4, row_shr:4) by (lane&4): row_shr:N is
//   D[i]=S[i-N], row_shl:N is D[i]=S[i+N]; lanes zeroed by bound_ctrl are
//   exactly the lanes the cndmask rejects. xor16/xor32 cross 16-lane rows
//   -> stay on __shfl_xor (DS).
template<int CTRL>
__device__ __forceinline__ float dpp_xor(float x) {
    return __int_as_float(
        __builtin_amdgcn_mov_dpp(__float_as_int(x), CTRL, 0xF, 0xF, true));
}

__device__ __forceinline__ float dpp_xor4(float x, bool lane4) {
    const float up = __int_as_float(
        __builtin_amdgcn_mov_dpp(__float_as_int(x), 0x104, 0xF, 0xF, true)); // row_shl:4 -> S[i+4]
    const float dn = __int_as_float(
        __builtin_amdgcn_mov_dpp(__float_as_int(x), 0x114, 0xF, 0xF, true)); // row_shr:4 -> S[i-4]
    return lane4 ? dn : up;
}

// alpha = atan(t)/pi + 0.5 via minimax odd poly (deg 11) + rcp range
// reduction. |err| ~1e-7 in alpha; output threshold is 1.2e-2.
__device__ __forceinline__ float fast_alpha(float t) {
    const float at  = __builtin_fabsf(t);
    const bool inv  = at > 1.0f;
    const float z   = inv ? __builtin_amdgcn_rcpf(at) : at;
    const float s   = z * z;
    float p = -0.0117212f;
    p = __builtin_fmaf(p, s,  0.05265332f);
    p = __builtin_fmaf(p, s, -0.11643287f);
    p = __builtin_fmaf(p, s,  0.19354346f);
    p = __builtin_fmaf(p, s, -0.33262347f);
    p = __builtin_fmaf(p, s,  0.99997726f);
    float r = z * p;
    r = inv ? (1.5707963267948966f - r) : r;
    r = (t < 0.0f) ? -r : r;
    return __builtin_fmaf(r, 0.3183098861837907f, 0.5f);
}

// One 512-thread block (8 waves) per batch element.
//
// Forward: element i on lane (i&63) of wave (i>>6), in a register.
//   j in {1,2,4,8} -> DPP/VALU (30 layers); j in {16,32} -> shfl (9 layers,
//   DS); j in {64,128,256} -> ping-pong LDS + barrier (6 layers).
//   Alphas -> As[t][pair_ordinal]. Fully unrolled (compile-time lg).
//
// Backward: out row kk = row (511-kk) of L45*...*L1*I; propagate one-hot row
//   vectors through layers in reverse (pair matrix symmetric -> same update
//   form). 8 waves x 2 rows/wave, element i at (lane=i>>3, slot=i&7).
//   j>=8: lane-xor lm=j>>3: lm in {1,2,4,8} -> DPP/VALU (18 of 21 layers),
//   lm in {16,32} -> shfl (3 layers). j<8 -> in-register slot pairs.
//   Alpha float4 loads shared by both rows. Fully unrolled.
__global__ __launch_bounds__(512, 2)
void difftopk_kernel(const float* __restrict__ x_in, float* __restrict__ out) {
    __shared__ float xs[2][N];
    __shared__ __align__(16) float As[NLAYERS][NPAIRS];

    const int b     = blockIdx.x;
    const int e     = threadIdx.x;   // element 0..511
    const int lane  = e & 63;
    const bool lane4 = (lane & 4) != 0;

    // ---------------- forward ----------------
    float o = x_in[(size_t)b * N + e];

    int t = 0, par = 0;
    #pragma unroll
    for (int s = 1; s <= 9; ++s) {
        const int k  = 1 << s;
        const bool kb = (e & k) == 0;
        #pragma unroll
        for (int lg = s - 1; lg >= 0; --lg, ++t) {
            const int j = 1 << lg;
            float p;
            if (lg >= 6) {              // cross-wave: LDS ping-pong
                xs[par][e] = o;
                __syncthreads();
                p = xs[par][e ^ j];
                par ^= 1;
            } else if (lg == 0) {
                p = dpp_xor<0xB1>(o);
            } else if (lg == 1) {
                p = dpp_xor<0x4E>(o);
            } else if (lg == 2) {
                p = dpp_xor4(o, lane4);
            } else if (lg == 3) {
                p = dpp_xor<0x128>(o);
            } else {                    // j in {16,32}
                p = __shfl_xor(o, j, 64);
            }
            const bool jb = (e & j) == 0;
            const float d = (kb == jb) ? (p - o) : (o - p);   // c - a
            const float alpha = fast_alpha(d * 10.0f);
            o = __builtin_fmaf(alpha, o - p, p);              // alpha*o+(1-alpha)*p
            if (jb) {
                const int ord = ((e >> (lg + 1)) << lg) | (e & (j - 1));
                As[t][ord] = alpha;
            }
        }
    }
    __syncthreads();   // publish all alphas

    // ---------------- backward ----------------
    const int wave  = e >> 6;          // 0..7 -> rows kk = wave, wave+8
    const int lane8 = lane << 3;
    const int r0 = N - 1 - wave;
    const int r1 = N - 1 - (wave + 8);

    float v0[8], v1[8];
    #pragma unroll
    for (int m = 0; m < 8; ++m) {
        v0[m] = (lane8 + m == r0) ? 1.0f : 0.0f;
        v1[m] = (lane8 + m == r1) ? 1.0f : 0.0f;
    }

    #pragma unroll
    for (int s = 9; s >= 1; --s) {
        const int base = (s * (s - 1)) >> 1;
        #pragma unroll
        for (int lg = 0; lg < s; ++lg) {
            const int tt = base + (s - 1 - lg);
            if (lg >= 3) {
                const int j    = 1 << lg;
                const int ordb = ((lane8 >> (lg + 1)) << lg) | (lane8 & (j - 1));
                const float4 a0 = *(const float4*)&As[tt][ordb];
                const float4 a1 = *(const float4*)&As[tt][ordb + 4];
                const float al[8] = {a0.x, a0.y, a0.z, a0.w, a1.x, a1.y, a1.z, a1.w};
                #pragma unroll
                for (int m = 0; m < 8; ++m) {
                    float p0, p1;
                    if (lg == 3)      { p0 = dpp_xor<0xB1>(v0[m]);   p1 = dpp_xor<0xB1>(v1[m]);   }
                    else if (lg == 4) { p0 = dpp_xor<0x4E>(v0[m]);   p1 = dpp_xor<0x4E>(v1[m]);   }
                    else if (lg == 5) { p0 = dpp_xor4(v0[m], lane4); p1 = dpp_xor4(v1[m], lane4); }
                    else if (lg == 6) { p0 = dpp_xor<0x128>(v0[m]);  p1 = dpp_xor<0x128>(v1[m]);  }
                    else              { p0 = __shfl_xor(v0[m], j >> 3, 64);
                                        p1 = __shfl_xor(v1[m], j >> 3, 64); }
                    v0[m] = __builtin_fmaf(al[m], v0[m] - p0, p0);
                    v1[m] = __builtin_fmaf(al[m], v1[m] - p1, p1);
                }
            } else {
                const float4 a = *(const float4*)&As[tt][lane << 2];
                const float aa[4] = {a.x, a.y, a.z, a.w};
                if (lg == 2) {
                    #pragma unroll
                    for (int i = 0; i < 4; ++i) {
                        const float d0 = v0[i] - v0[i + 4], d1 = v1[i] - v1[i + 4];
                        const float x0 = v0[i], y0 = v0[i + 4];
                        const float x1 = v1[i], y1 = v1[i + 4];
                        v0[i]     = __builtin_fmaf(aa[i],  d0, y0);
                        v0[i + 4] = __builtin_fmaf(aa[i], -d0, x0);
                        v1[i]     = __builtin_fmaf(aa[i],  d1, y1);
                        v1[i + 4] = __builtin_fmaf(aa[i], -d1, x1);
                    }
                } else if (lg == 1) {
                    #pragma unroll
                    for (int i = 0; i < 4; ++i) {
                        const int lo = (((i >> 1) << 2) | (i & 1));
                        const float d0 = v0[lo] - v0[lo + 2], d1 = v1[lo] - v1[lo + 2];
                        const float x0 = v0[lo], y0 = v0[lo + 2];
                        const float x1 = v1[lo], y1 = v1[lo + 2];
                        v0[lo]     = __builtin_fmaf(aa[i],  d0, y0);
                        v0[lo + 2] = __builtin_fmaf(aa[i], -d0, x0);
                        v1[lo]     = __builtin_fmaf(aa[i],  d1, y1);
                        v1[lo + 2] = __builtin_fmaf(aa[i], -d1, x1);
                    }
                } else {
                    #pragma unroll
                    for (int i = 0; i < 4; ++i) {
                        const int lo = i << 1;
                        const float d0 = v0[lo] - v0[lo + 1], d1 = v1[lo] - v1[lo + 1];
                        const float x0 = v0[lo], y0 = v0[lo + 1];
                        const float x1 = v1[lo], y1 = v1[lo + 1];
                        v0[lo]     = __builtin_fmaf(aa[i],  d0, y0);
                        v0[lo + 1] = __builtin_fmaf(aa[i], -d0, x0);
                        v1[lo]     = __builtin_fmaf(aa[i],  d1, y1);
                        v1[lo + 1] = __builtin_fmaf(aa[i], -d1, x1);
                    }
                }
            }
        }
    }

    // ---------------- write out ----------------
    float4* dst0 = (float4*)(out + ((size_t)b * KTOP + wave) * N + lane8);
    dst0[0] = make_float4(v0[0], v0[1], v0[2], v0[3]);
    dst0[1] = make_float4(v0[4], v0[5], v0[6], v0[7]);
    float4* dst1 = (float4*)(out + ((size_t)b * KTOP + wave + 8) * N + lane8);
    dst1[0] = make_float4(v1[0], v1[1], v1[2], v1[3]);
    dst1[1] = make_float4(v1[4], v1[5], v1[6], v1[7]);
}

extern "C" void kernel_launch(void* const* d_in, const int* in_sizes, int n_in,
                              void* d_out, int out_size, void* d_ws, size_t ws_size,
                              hipStream_t stream) {
    const float* x = (const float*)d_in[0];
    float* out = (float*)d_out;
    difftopk_kernel<<<dim3(BATCH), dim3(512), 0, stream>>>(x, out);
}

// Round 9
// 65.837 us; speedup vs baseline: 1.0041x; 1.0041x over previous
//
#include <hip/hip_runtime.h>
#include <math.h>

#define N 512
#define BATCH 256
#define KTOP 16
#define NLAYERS 45
#define NPAIRS 256

typedef float f32x2 __attribute__((ext_vector_type(2)));

// Cross-lane xor via DPP (VALU pipe, NOT the DS pipe):
//   xor1 = quad_perm[1,0,3,2] = 0xB1; xor2 = quad_perm[2,3,0,1] = 0x4E;
//   xor8 = row_ror:8 = 0x128 (rotate by half a 16-lane row == xor 8).
//   xor4/16/32 stay on __shfl_xor (DS pipe has idle capacity; a bpermute
//   is 1 issue slot vs 3 VALU ops -- R8 measured the VALU version as a
//   slight regression in this VALU-bound regime).
template<int CTRL>
__device__ __forceinline__ float dpp_xor(float x) {
    return __int_as_float(
        __builtin_amdgcn_mov_dpp(__float_as_int(x), CTRL, 0xF, 0xF, true));
}

template<int CTRL>
__device__ __forceinline__ f32x2 dpp_xor2(f32x2 x) {
    f32x2 r;
    r.x = dpp_xor<CTRL>(x.x);
    r.y = dpp_xor<CTRL>(x.y);
    return r;
}

__device__ __forceinline__ f32x2 shfl_xor2(f32x2 x, int lm) {
    f32x2 r;
    r.x = __shfl_xor(x.x, lm, 64);
    r.y = __shfl_xor(x.y, lm, 64);
    return r;
}

// alpha = atan(t)/pi + 0.5 via minimax odd poly (deg 11) + rcp range
// reduction. |err| ~1e-7 in alpha; output threshold is 1.2e-2.
__device__ __forceinline__ float fast_alpha(float t) {
    const float at  = __builtin_fabsf(t);
    const bool inv  = at > 1.0f;
    const float z   = inv ? __builtin_amdgcn_rcpf(at) : at;
    const float s   = z * z;
    float p = -0.0117212f;
    p = __builtin_fmaf(p, s,  0.05265332f);
    p = __builtin_fmaf(p, s, -0.11643287f);
    p = __builtin_fmaf(p, s,  0.19354346f);
    p = __builtin_fmaf(p, s, -0.33262347f);
    p = __builtin_fmaf(p, s,  0.99997726f);
    float r = z * p;
    r = inv ? (1.5707963267948966f - r) : r;
    r = (t < 0.0f) ? -r : r;
    return __builtin_fmaf(r, 0.3183098861837907f, 0.5f);
}

// One 512-thread block (8 waves) per batch element.
//
// Forward (R6 structure): element i on lane (i&63) of wave (i>>6), in a
//   register. j in {1,2,8} -> DPP; j in {4,16,32} -> shfl; j in
//   {64,128,256} -> ping-pong LDS + barrier. Alphas -> As[t][pair_ordinal].
//
// Backward (PACKED): out row kk = row (511-kk) of L45*...*L1*I; propagate
//   one-hot row vectors in reverse (pair matrix symmetric -> same update
//   form). 8 waves x 2 rows/wave packed as f32x2 -> v_pk_fma_f32 halves the
//   FMA/sub issue count. Element i at (lane=i>>3, slot=i&7). j>=8: lane-xor
//   lm=j>>3: {1,2,8} -> DPP, {4,16,32} -> shfl. j<8 -> in-register slot
//   pairs, all pk ops. Fully unrolled.
__global__ __launch_bounds__(512, 2)
void difftopk_kernel(const float* __restrict__ x_in, float* __restrict__ out) {
    __shared__ float xs[2][N];
    __shared__ __align__(16) float As[NLAYERS][NPAIRS];

    const int b    = blockIdx.x;
    const int e    = threadIdx.x;   // element 0..511
    const int lane = e & 63;

    // ---------------- forward ----------------
    float o = x_in[(size_t)b * N + e];

    int t = 0, par = 0;
    #pragma unroll
    for (int s = 1; s <= 9; ++s) {
        const int k  = 1 << s;
        const bool kb = (e & k) == 0;
        #pragma unroll
        for (int lg = s - 1; lg >= 0; --lg, ++t) {
            const int j = 1 << lg;
            float p;
            if (lg >= 6) {              // cross-wave: LDS ping-pong
                xs[par][e] = o;
                __syncthreads();
                p = xs[par][e ^ j];
                par ^= 1;
            } else if (lg == 0) {
                p = dpp_xor<0xB1>(o);
            } else if (lg == 1) {
                p = dpp_xor<0x4E>(o);
            } else if (lg == 3) {
                p = dpp_xor<0x128>(o);
            } else {                    // j in {4,16,32}
                p = __shfl_xor(o, j, 64);
            }
            const bool jb = (e & j) == 0;
            const float d = (kb == jb) ? (p - o) : (o - p);   // c - a
            const float alpha = fast_alpha(d * 10.0f);
            o = __builtin_fmaf(alpha, o - p, p);              // alpha*o+(1-alpha)*p
            if (jb) {
                const int ord = ((e >> (lg + 1)) << lg) | (e & (j - 1));
                As[t][ord] = alpha;
            }
        }
    }
    __syncthreads();   // publish all alphas

    // ---------------- backward (two rows packed per lane) ----------------
    const int wave  = e >> 6;          // 0..7 -> rows kk = wave, wave+8
    const int lane8 = lane << 3;
    const int r0 = N - 1 - wave;
    const int r1 = N - 1 - (wave + 8);

    f32x2 w[8];
    #pragma unroll
    for (int m = 0; m < 8; ++m) {
        w[m].x = (lane8 + m == r0) ? 1.0f : 0.0f;
        w[m].y = (lane8 + m == r1) ? 1.0f : 0.0f;
    }

    #pragma unroll
    for (int s = 9; s >= 1; --s) {
        const int base = (s * (s - 1)) >> 1;
        #pragma unroll
        for (int lg = 0; lg < s; ++lg) {
            const int tt = base + (s - 1 - lg);
            if (lg >= 3) {
                const int j    = 1 << lg;
                const int ordb = ((lane8 >> (lg + 1)) << lg) | (lane8 & (j - 1));
                const float4 a0 = *(const float4*)&As[tt][ordb];
                const float4 a1 = *(const float4*)&As[tt][ordb + 4];
                const float al[8] = {a0.x, a0.y, a0.z, a0.w, a1.x, a1.y, a1.z, a1.w};
                #pragma unroll
                for (int m = 0; m < 8; ++m) {
                    f32x2 p;
                    if (lg == 3)      p = dpp_xor2<0xB1>(w[m]);
                    else if (lg == 4) p = dpp_xor2<0x4E>(w[m]);
                    else if (lg == 6) p = dpp_xor2<0x128>(w[m]);
                    else              p = shfl_xor2(w[m], j >> 3);
                    const f32x2 a2 = {al[m], al[m]};
                    w[m] = __builtin_elementwise_fma(a2, w[m] - p, p);
                }
            } else {
                const float4 a = *(const float4*)&As[tt][lane << 2];
                const float aa[4] = {a.x, a.y, a.z, a.w};
                if (lg == 2) {
                    #pragma unroll
                    for (int i = 0; i < 4; ++i) {
                        const f32x2 a2 = {aa[i], aa[i]};
                        const f32x2 d  = w[i] - w[i + 4];
                        const f32x2 lo = __builtin_elementwise_fma(a2,  d, w[i + 4]);
                        const f32x2 hi = __builtin_elementwise_fma(a2, -d, w[i]);
                        w[i] = lo; w[i + 4] = hi;
                    }
                } else if (lg == 1) {
                    #pragma unroll
                    for (int i = 0; i < 4; ++i) {
                        const int lo_i = (((i >> 1) << 2) | (i & 1));
                        const f32x2 a2 = {aa[i], aa[i]};
                        const f32x2 d  = w[lo_i] - w[lo_i + 2];
                        const f32x2 lo = __builtin_elementwise_fma(a2,  d, w[lo_i + 2]);
                        const f32x2 hi = __builtin_elementwise_fma(a2, -d, w[lo_i]);
                        w[lo_i] = lo; w[lo_i + 2] = hi;
                    }
                } else {
                    #pragma unroll
                    for (int i = 0; i < 4; ++i) {
                        const int lo_i = i << 1;
                        const f32x2 a2 = {aa[i], aa[i]};
                        const f32x2 d  = w[lo_i] - w[lo_i + 1];
                        const f32x2 lo = __builtin_elementwise_fma(a2,  d, w[lo_i + 1]);
                        const f32x2 hi = __builtin_elementwise_fma(a2, -d, w[lo_i]);
                        w[lo_i] = lo; w[lo_i + 1] = hi;
                    }
                }
            }
        }
    }

    // ---------------- write out ----------------
    float4* dst0 = (float4*)(out + ((size_t)b * KTOP + wave) * N + lane8);
    dst0[0] = make_float4(w[0].x, w[1].x, w[2].x, w[3].x);
    dst0[1] = make_float4(w[4].x, w[5].x, w[6].x, w[7].x);
    float4* dst1 = (float4*)(out + ((size_t)b * KTOP + wave + 8) * N + lane8);
    dst1[0] = make_float4(w[0].y, w[1].y, w[2].y, w[3].y);
    dst1[1] = make_float4(w[4].y, w[5].y, w[6].y, w[7].y);
}

extern "C" void kernel_launch(void* const* d_in, const int* in_sizes, int n_in,
                              void* d_out, int out_size, void* d_ws, size_t ws_size,
                              hipStream_t stream) {
    const float* x = (const float*)d_in[0];
    float* out = (float*)d_out;
    difftopk_kernel<<<dim3(BATCH), dim3(512), 0, stream>>>(x, out);
}